// Round 8
// baseline (73.753 us; speedup 1.0000x reference)
//
#include <hip/hip_runtime.h>
#include <hip/hip_bf16.h>

// Decoder: B=1024, C=8, T=32, E=128, H=256, SEG=64, STEP=32, SIG=1056. f32 I/O.
// Wc = Winv@W2 (64x256), bc = Winv@b2+binv. Per (b,c):
//   Hm = relu(X W1^T + b1); S = Hm Wc^T + bc; sig = overlap-add(S)/counter;
//   out[b] = conv1d_{C->1,k=3,pad1}(sig) + bconv.
// R28: R23 EXACT STRUCTURE (proven 59.1us; splits/barrier-removal/occupancy
//   all lost in R24-R27) + in-wave software pipeline of the nc loop:
//     old: GEMM1(nc) -> Hwrite(nc) -> bh read (~150cy exposed) -> GEMM2(nc)
//     new: Hwrite(nc) -> issue bh reads -> GEMM1(nc+1) covers the LDS
//          round-trip -> GEMM2(nc); Wcpre(nc+1) load at loop bottom
//          (covered by next Hwrite+bhread+GEMM1).
//   Register-neutral: acc1 consumed by Hwrite before GEMM1(nc+1) refills it;
//   peak liveness == R23's (112V+64A, no spill). All hazards identical to
//   R23's proven ordering (per-wave DS ops in-order; bh in regs before
//   region overwrite). Everything else verbatim R23.

typedef __bf16 bf16x8 __attribute__((ext_vector_type(8)));
typedef float  f32x4  __attribute__((ext_vector_type(4)));
typedef unsigned int u32;
typedef u32 u32x2 __attribute__((ext_vector_type(2)));

#define L_W1   0        // 65536 B  W1 frag layout
#define L_HS   65536    // 36864 B  8 waves x [32][72] bf16 H; S alias [32][68]
#define L_SGA  102400   // 17024 B  sigA bf16 [8][1064] (pads zeroed)
#define L_SGB  119424   // 17024 B  sigB bf16 [8][1064]
#define L_B1   136448   // 1024 B
#define L_BC   137472   // 256 B
#define L_WV   137728   // 128 B
#define LDS_SZ 137856

// LDS-only barrier: waves' DS writes visible, global loads stay in flight.
#define BAR_LDS() do {                                              \
    __builtin_amdgcn_sched_barrier(0);                              \
    asm volatile("s_waitcnt lgkmcnt(0)" ::: "memory");              \
    __builtin_amdgcn_s_barrier();                                   \
    __builtin_amdgcn_sched_barrier(0);                              \
  } while (0)

static __device__ __forceinline__ bf16x8 cvt8(f32x4 a, f32x4 b) {
  bf16x8 r;
  r[0] = (__bf16)a[0]; r[1] = (__bf16)a[1]; r[2] = (__bf16)a[2]; r[3] = (__bf16)a[3];
  r[4] = (__bf16)b[0]; r[5] = (__bf16)b[1]; r[6] = (__bf16)b[2]; r[7] = (__bf16)b[3];
  return r;
}
static __device__ __forceinline__ u32 packbf2(float a, float b) {
  union { __hip_bfloat16 h; unsigned short s; } ua, ub;
  ua.h = __float2bfloat16(a); ub.h = __float2bfloat16(b);
  return (u32)ua.s | ((u32)ub.s << 16);
}
static __device__ __forceinline__ float lo16f(u32 w) { return __uint_as_float(w << 16); }
static __device__ __forceinline__ float hi16f(u32 w) { return __uint_as_float(w & 0xffff0000u); }

// ---- prep: Wc = Winv@W2 frag layout; bc = Winv@b2 + binv (proven) ----------
__global__ __launch_bounds__(256) void k_precomp(
    const float* __restrict__ W2, const float* __restrict__ b2,
    const float* __restrict__ Winv, const float* __restrict__ binv,
    __hip_bfloat16* __restrict__ Wcpre, float* __restrict__ bc) {
  __shared__ float wrow[128];
  const int s = blockIdx.x, h = threadIdx.x;
  if (h < 128) wrow[h] = Winv[s * 128 + h];
  __syncthreads();
  float acc = 0.f;
  #pragma unroll 8
  for (int e = 0; e < 128; ++e) acc = fmaf(wrow[e], W2[e * 256 + h], acc);
  const int nc = h >> 6, ks2 = (h >> 5) & 1, g = (h >> 3) & 3, j = h & 7;
  const int nt2 = s >> 4, q = s & 15;
  Wcpre[((((nc * 2 + ks2) * 4 + nt2) * 4 + g) * 16 + q) * 8 + j] = __float2bfloat16(acc);
  if (h == 0) {
    float a = binv[s];
    for (int e = 0; e < 128; ++e) a = fmaf(wrow[e], b2[e], a);
    bc[s] = a;
  }
}

// ---- fused kernel: stage-W1 -> pipelined GEMM1/GEMM2 -> overlap-add -> conv
__global__ __launch_bounds__(512)
__attribute__((amdgpu_waves_per_eu(2, 2)))
void k_gemm(const float* __restrict__ X,      // (1024,8,32,128)
            const float* __restrict__ W1,     // (256,128) raw f32
            const float* __restrict__ b1,     // (256)
            const __hip_bfloat16* __restrict__ Wcpre,   // frag layout, L2
            const float* __restrict__ bcp,    // (64)
            const float* __restrict__ Wcv,    // (24)
            const float* __restrict__ bcv,    // (1)
            float* __restrict__ Out)          // (1024, 1056) f32
{
  extern __shared__ __align__(16) char smem[];
  const int tid = threadIdx.x;
  const int wave = tid >> 6, lane = tid & 63;
  const int q = lane & 15, g = lane >> 4;
  const int c = wave;
  const int b0 = blockIdx.x * 4;

  f32x4 xa[16];
  #define LOADX(bb) do {                                                        \
    _Pragma("unroll")                                                           \
    for (int _mt = 0; _mt < 2; ++_mt) {                                         \
      const float* _s = X + ((size_t)((bb) * 8 + c)) * 4096                     \
                          + (_mt * 16 + q) * 128 + g * 8;                       \
      _Pragma("unroll")                                                         \
      for (int _ks = 0; _ks < 4; ++_ks) {                                       \
        xa[(_mt * 4 + _ks) * 2 + 0] = *reinterpret_cast<const f32x4*>(_s + _ks * 32);     \
        xa[(_mt * 4 + _ks) * 2 + 1] = *reinterpret_cast<const f32x4*>(_s + _ks * 32 + 4); \
      } } } while (0)

  // issue iter-0 X loads FIRST; they fly under W1 staging + barrier
  LOADX(b0);

  // ---- stage W1 frags from RAW f32 W1; small tensors; sig pads ----
  #pragma unroll
  for (int i = 0; i < 8; ++i) {
    const int p8 = tid + i * 512;
    const int fq = p8 & 15, fg = (p8 >> 4) & 3, fks = (p8 >> 6) & 3;
    const int fnt = (p8 >> 8) & 3, fnc = (p8 >> 10) & 3;
    const float* src = W1 + (fnc * 64 + fnt * 16 + fq) * 128 + fks * 32 + fg * 8;
    *reinterpret_cast<bf16x8*>(smem + L_W1 + p8 * 16) =
        cvt8(*reinterpret_cast<const f32x4*>(src),
             *reinterpret_cast<const f32x4*>(src + 4));
  }
  {
    if (tid < 256)               ((float*)(smem + L_B1))[tid]       = b1[tid];
    if (tid >= 256 && tid < 320) ((float*)(smem + L_BC))[tid - 256] = bcp[tid - 256];
    if (tid >= 320 && tid < 344) ((float*)(smem + L_WV))[tid - 320] = Wcv[tid - 320];
    if (tid == 344)              ((float*)(smem + L_WV))[24]        = bcv[0];
    if (tid >= 384 && tid < 448) {   // zero pad cols [cc][1056..1063] x2 bufs
      const int t = tid - 384, buf = t >> 5, cc = (t & 31) >> 2, k = t & 3;
      *reinterpret_cast<u32*>(
          reinterpret_cast<__hip_bfloat16*>(smem + (buf ? L_SGB : L_SGA))
          + cc * 1064 + 1056 + 2 * k) = 0u;
    }
  }
  BAR_LDS();   // one-time: LDS writes visible; xa loads stay in flight

  __hip_bfloat16* Hb = reinterpret_cast<__hip_bfloat16*>(smem + L_HS) + wave * 2304;
  const float* smB1 = (const float*)(smem + L_B1);
  const float* smBC = (const float*)(smem + L_BC);
  const float* smWV = (const float*)(smem + L_WV);

  // ---- pipelined nc-loop building blocks --------------------------------
  #define LOADW2(ncx) do {                                                      \
    _Pragma("unroll")                                                           \
    for (int _k = 0; _k < 2; ++_k)                                              \
      _Pragma("unroll")                                                         \
      for (int _n = 0; _n < 4; ++_n)                                            \
        bw2f[_k][_n] = *reinterpret_cast<const bf16x8*>(                        \
            Wcpre + (((ncx) * 2 + _k) * 4 + _n) * 512 + lane * 8);              \
  } while (0)

  #define GEMM1(ncx) do {                                                       \
    _Pragma("unroll")                                                           \
    for (int _m = 0; _m < 2; ++_m)                                              \
      _Pragma("unroll")                                                         \
      for (int _n = 0; _n < 4; ++_n)                                            \
        acc1[_m][_n] = (f32x4){0.f, 0.f, 0.f, 0.f};                             \
    _Pragma("unroll")                                                           \
    for (int _ks = 0; _ks < 4; ++_ks) {                                         \
      bf16x8 _bw[4];                                                            \
      _Pragma("unroll")                                                         \
      for (int _n = 0; _n < 4; ++_n)                                            \
        _bw[_n] = *reinterpret_cast<const bf16x8*>(                             \
            smem + L_W1 + ((((ncx) * 4 + _n) * 4 + _ks) << 10) + lane * 16);    \
      __builtin_amdgcn_s_setprio(1);                                            \
      _Pragma("unroll")                                                         \
      for (int _n = 0; _n < 4; ++_n) {                                          \
        acc1[0][_n] = __builtin_amdgcn_mfma_f32_16x16x32_bf16(_bw[_n], af[0][_ks], acc1[0][_n], 0, 0, 0); \
        acc1[1][_n] = __builtin_amdgcn_mfma_f32_16x16x32_bf16(_bw[_n], af[1][_ks], acc1[1][_n], 0, 0, 0); \
      }                                                                         \
      __builtin_amdgcn_s_setprio(0);                                            \
    }                                                                           \
  } while (0)

  #define HWRITE(ncx) do {                                                      \
    _Pragma("unroll")                                                           \
    for (int _n = 0; _n < 4; ++_n) {                                            \
      const f32x4 _b1q = *reinterpret_cast<const f32x4*>(                       \
          smB1 + (ncx) * 64 + _n * 16 + 4 * g);                                 \
      _Pragma("unroll")                                                         \
      for (int _m = 0; _m < 2; ++_m) {                                          \
        u32x2 _w;                                                               \
        _w[0] = packbf2(fmaxf(acc1[_m][_n][0] + _b1q[0], 0.f),                  \
                        fmaxf(acc1[_m][_n][1] + _b1q[1], 0.f));                 \
        _w[1] = packbf2(fmaxf(acc1[_m][_n][2] + _b1q[2], 0.f),                  \
                        fmaxf(acc1[_m][_n][3] + _b1q[3], 0.f));                 \
        *reinterpret_cast<u32x2*>(Hb + (_m * 16 + q) * 72 + _n * 16 + 4 * g) = _w; \
      }                                                                         \
    }                                                                           \
  } while (0)

  #define BHREAD() do {                                                         \
    _Pragma("unroll")                                                           \
    for (int _k = 0; _k < 2; ++_k)                                              \
      _Pragma("unroll")                                                         \
      for (int _m = 0; _m < 2; ++_m)                                            \
        bh[_k][_m] = *reinterpret_cast<const bf16x8*>(                          \
            Hb + (_m * 16 + q) * 72 + _k * 32 + g * 8);                         \
  } while (0)

  #define GEMM2() do {                                                          \
    _Pragma("unroll")                                                           \
    for (int _k = 0; _k < 2; ++_k) {                                            \
      __builtin_amdgcn_s_setprio(1);                                            \
      _Pragma("unroll")                                                         \
      for (int _n = 0; _n < 4; ++_n) {                                          \
        acc2[0][_n] = __builtin_amdgcn_mfma_f32_16x16x32_bf16(bw2f[_k][_n], bh[_k][0], acc2[0][_n], 0, 0, 0); \
        acc2[1][_n] = __builtin_amdgcn_mfma_f32_16x16x32_bf16(bw2f[_k][_n], bh[_k][1], acc2[1][_n], 0, 0, 0); \
      }                                                                         \
      __builtin_amdgcn_s_setprio(0);                                            \
    }                                                                           \
  } while (0)

  #pragma unroll 1
  for (int it = 0; it < 4; ++it) {
    // consume prefetched X -> bf16 frags
    bf16x8 af[2][4];
    #pragma unroll
    for (int f = 0; f < 8; ++f) af[f >> 2][f & 3] = cvt8(xa[2 * f], xa[2 * f + 1]);

    f32x4 acc2[2][4] = {};   // S^T frag: col t = mt*16+q, row s = nt2*16+4g+i
    f32x4 acc1[2][4];
    bf16x8 bw2f[2][4];
    bf16x8 bh[2][2];

    // pipeline prologue: Wcpre(0) covered by GEMM1(0)
    LOADW2(0);
    GEMM1(0);

    #pragma unroll 1         // keep rolled: blocks cross-chunk load hoisting
    for (int nc = 0; nc < 3; ++nc) {
      HWRITE(nc);            // consume acc1(nc) -> LDS
      BHREAD();              // issue the H round-trip reads now...
      GEMM1(nc + 1);         // ...and cover them with 32 independent MFMAs
      GEMM2();               // bh has landed; bw2f(nc) from last iteration
      LOADW2(nc + 1);        // covered by next HWRITE+BHREAD+GEMM1
    }
    HWRITE(3);
    BHREAD();
    GEMM2();

    // issue next batch's X loads AFTER all Wcpre loads of this iteration:
    // vmcnt retires in order, so fragment waits never drain the X prefetch.
    if (it < 3) LOADX(b0 + it + 1);

    // per-wave: S -> own H region [32 t][68 s] (packed b64)
    __hip_bfloat16* Sl = Hb;
    #pragma unroll
    for (int nt2 = 0; nt2 < 4; ++nt2) {
      const f32x4 bcq = *reinterpret_cast<const f32x4*>(smBC + nt2 * 16 + 4 * g);
      #pragma unroll
      for (int mt = 0; mt < 2; ++mt) {
        u32x2 w;
        w[0] = packbf2(acc2[mt][nt2][0] + bcq[0], acc2[mt][nt2][1] + bcq[1]);
        w[1] = packbf2(acc2[mt][nt2][2] + bcq[2], acc2[mt][nt2][3] + bcq[3]);
        *reinterpret_cast<u32x2*>(Sl + (mt * 16 + q) * 68 + nt2 * 16 + 4 * g) = w;
      }
    }

    // overlap-add gather + normalize -> bf16 sig[it&1][c][0..1055], 4/lane
    {
      __hip_bfloat16* sigc = reinterpret_cast<__hip_bfloat16*>(
          smem + ((it & 1) ? L_SGB : L_SGA)) + c * 1064;
      #pragma unroll
      for (int w = 0; w < 5; ++w) {
        const int u = w * 64 + lane;
        if (u < 264) {
          const int p = 4 * u, t = p >> 5, j = p & 31;
          u32x2 r1 = {0u, 0u}, r2 = {0u, 0u};
          if (t < 32) r1 = *reinterpret_cast<const u32x2*>(Sl + t * 68 + j);
          if (t > 0)  r2 = *reinterpret_cast<const u32x2*>(Sl + (t - 1) * 68 + j + 32);
          const float nrm = (t == 0 || t == 32) ? 1.f : 0.5f;
          u32x2 wv;
          wv[0] = packbf2(nrm * (lo16f(r1[0]) + lo16f(r2[0])),
                          nrm * (hi16f(r1[0]) + hi16f(r2[0])));
          wv[1] = packbf2(nrm * (lo16f(r1[1]) + lo16f(r2[1])),
                          nrm * (hi16f(r1[1]) + hi16f(r2[1])));
          *reinterpret_cast<u32x2*>(sigc + p) = wv;
        }
      }
    }

    // paired conv on odd iters: one pass over both batches, 528 quads
    if (it & 1) {
      BAR_LDS();   // both sig buffers complete for all 8 channels
      const float bconv = smWV[24];
      #pragma unroll 1
      for (int rr = 0; rr < 2; ++rr) {
        const int u = tid + rr * 512;
        if (u < 528) {
          const int half = (u >= 264) ? 1 : 0;
          const __hip_bfloat16* sg = reinterpret_cast<const __hip_bfloat16*>(
              smem + (half ? L_SGB : L_SGA));
          const int p0 = (u - half * 264) * 4;
          f32x4 acc = {bconv, bconv, bconv, bconv};
          #pragma unroll
          for (int cc = 0; cc < 8; ++cc) {
            const __hip_bfloat16* row = sg + cc * 1064;
            const u32 wm = (p0 > 0) ? *reinterpret_cast<const u32*>(row + p0 - 2) : 0u;
            const u32x2 wc = *reinterpret_cast<const u32x2*>(row + p0);
            const u32 wr = *reinterpret_cast<const u32*>(row + p0 + 4);
            const float l  = hi16f(wm);
            const float a0 = lo16f(wc[0]), a1 = hi16f(wc[0]);
            const float a2 = lo16f(wc[1]), a3 = hi16f(wc[1]);
            const float r  = lo16f(wr);
            const float w0 = smWV[cc * 3], w1 = smWV[cc * 3 + 1], w2 = smWV[cc * 3 + 2];
            acc[0] = fmaf(w0, l,  fmaf(w1, a0, fmaf(w2, a1, acc[0])));
            acc[1] = fmaf(w0, a0, fmaf(w1, a1, fmaf(w2, a2, acc[1])));
            acc[2] = fmaf(w0, a1, fmaf(w1, a2, fmaf(w2, a3, acc[2])));
            acc[3] = fmaf(w0, a2, fmaf(w1, a3, fmaf(w2, r,  acc[3])));
          }
          *reinterpret_cast<f32x4*>(
              Out + (size_t)(b0 + it - 1 + half) * 1056 + p0) = acc;
        }
      }
      if (it != 3) BAR_LDS();   // conv reads done before next pair's gathers
    }
  }
  #undef LOADX
  #undef LOADW2
  #undef GEMM1
  #undef HWRITE
  #undef BHREAD
  #undef GEMM2
}

extern "C" void kernel_launch(void* const* d_in, const int* in_sizes, int n_in,
                              void* d_out, int out_size, void* d_ws, size_t ws_size,
                              hipStream_t stream) {
  const float* X    = (const float*)d_in[0];
  const float* W1   = (const float*)d_in[1];
  const float* b1   = (const float*)d_in[2];
  const float* W2   = (const float*)d_in[3];
  const float* b2   = (const float*)d_in[4];
  const float* Winv = (const float*)d_in[5];
  const float* binv = (const float*)d_in[6];
  const float* Wcv  = (const float*)d_in[7];
  const float* bcv  = (const float*)d_in[8];

  __hip_bfloat16* Wcpre = (__hip_bfloat16*)((char*)d_ws + 65536);    // 32768 B
  float*          bcp   = (float*)((char*)d_ws + 98304);             // 256 B

  k_precomp<<<64, 256, 0, stream>>>(W2, b2, Winv, binv, Wcpre, bcp);
  k_gemm<<<256, 512, LDS_SZ, stream>>>(X, W1, b1, Wcpre, bcp, Wcv, bcv,
                                       (float*)d_out);
}

// Round 9
// 58.839 us; speedup vs baseline: 1.2535x; 1.2535x over previous
//
#include <hip/hip_runtime.h>
#include <hip/hip_bf16.h>

// Decoder: B=1024, C=8, T=32, E=128, H=256, SEG=64, STEP=32, SIG=1056. f32 I/O.
// Wc = Winv@W2 (64x256), bc = Winv@b2+binv. Per (b,c):
//   Hm = relu(X W1^T + b1); S = Hm Wc^T + bc; sig = overlap-add(S)/counter;
//   out[b] = conv1d_{C->1,k=3,pad1}(sig) + bconv.
// FINAL (R29 = R23 exact, proven 59.1us). Nine-round matrix:
//   - occupancy via reg-cap (waves_per_eu>=4): VGPR forced to 64/128 split,
//     ~100MB scratch spills, 2-9x regressions (R21/R22/R25).
//   - occupancy via structure (4-wave split, 12-wave shared-W1, half-tile):
//     77-102us; GEMM1 B-operand off LDS and/or lost amortization (R24-R26).
//   - barrier removal + conv split: 72.6us — barriers were ~free; the split's
//     global sig round-trip + lost overlap cost more (R27).
//   - in-wave nc-pipeline: +16 regs -> 128 VGPR + 42MB spill, 86us (R28).
//   Conclusion: kernel is latency-bound at a HW occupancy-quantization
//   ceiling (VGPR steps 64/128/256 -> 2 waves/SIMD for this ~176-reg
//   footprint). R23's schedule is the measured optimum:
//   (1) Wcpre GEMM2 fragments prefetched at nc-start (GEMM1 covers L2 lat),
//   (2) next-batch X prefetch AFTER all Wcpre loads (in-order vmcnt),
//   (3) #pragma unroll 1 on nc loop (blocks pressure-amplifying hoisting).

typedef __bf16 bf16x8 __attribute__((ext_vector_type(8)));
typedef float  f32x4  __attribute__((ext_vector_type(4)));
typedef unsigned int u32;
typedef u32 u32x2 __attribute__((ext_vector_type(2)));

#define L_W1   0        // 65536 B  W1 frag layout
#define L_HS   65536    // 36864 B  8 waves x [32][72] bf16 H; S alias [32][68]
#define L_SGA  102400   // 17024 B  sigA bf16 [8][1064] (pads zeroed)
#define L_SGB  119424   // 17024 B  sigB bf16 [8][1064]
#define L_B1   136448   // 1024 B
#define L_BC   137472   // 256 B
#define L_WV   137728   // 128 B
#define LDS_SZ 137856

// LDS-only barrier: waves' DS writes visible, global loads stay in flight.
#define BAR_LDS() do {                                              \
    __builtin_amdgcn_sched_barrier(0);                              \
    asm volatile("s_waitcnt lgkmcnt(0)" ::: "memory");              \
    __builtin_amdgcn_s_barrier();                                   \
    __builtin_amdgcn_sched_barrier(0);                              \
  } while (0)

static __device__ __forceinline__ bf16x8 cvt8(f32x4 a, f32x4 b) {
  bf16x8 r;
  r[0] = (__bf16)a[0]; r[1] = (__bf16)a[1]; r[2] = (__bf16)a[2]; r[3] = (__bf16)a[3];
  r[4] = (__bf16)b[0]; r[5] = (__bf16)b[1]; r[6] = (__bf16)b[2]; r[7] = (__bf16)b[3];
  return r;
}
static __device__ __forceinline__ u32 packbf2(float a, float b) {
  union { __hip_bfloat16 h; unsigned short s; } ua, ub;
  ua.h = __float2bfloat16(a); ub.h = __float2bfloat16(b);
  return (u32)ua.s | ((u32)ub.s << 16);
}
static __device__ __forceinline__ float lo16f(u32 w) { return __uint_as_float(w << 16); }
static __device__ __forceinline__ float hi16f(u32 w) { return __uint_as_float(w & 0xffff0000u); }

// ---- prep: Wc = Winv@W2 frag layout; bc = Winv@b2 + binv (proven) ----------
__global__ __launch_bounds__(256) void k_precomp(
    const float* __restrict__ W2, const float* __restrict__ b2,
    const float* __restrict__ Winv, const float* __restrict__ binv,
    __hip_bfloat16* __restrict__ Wcpre, float* __restrict__ bc) {
  __shared__ float wrow[128];
  const int s = blockIdx.x, h = threadIdx.x;
  if (h < 128) wrow[h] = Winv[s * 128 + h];
  __syncthreads();
  float acc = 0.f;
  #pragma unroll 8
  for (int e = 0; e < 128; ++e) acc = fmaf(wrow[e], W2[e * 256 + h], acc);
  const int nc = h >> 6, ks2 = (h >> 5) & 1, g = (h >> 3) & 3, j = h & 7;
  const int nt2 = s >> 4, q = s & 15;
  Wcpre[((((nc * 2 + ks2) * 4 + nt2) * 4 + g) * 16 + q) * 8 + j] = __float2bfloat16(acc);
  if (h == 0) {
    float a = binv[s];
    for (int e = 0; e < 128; ++e) a = fmaf(wrow[e], b2[e], a);
    bc[s] = a;
  }
}

// ---- fused kernel: stage-W1 -> GEMM1 -> GEMM2 -> overlap-add -> paired conv
__global__ __launch_bounds__(512)
__attribute__((amdgpu_waves_per_eu(2, 2)))
void k_gemm(const float* __restrict__ X,      // (1024,8,32,128)
            const float* __restrict__ W1,     // (256,128) raw f32
            const float* __restrict__ b1,     // (256)
            const __hip_bfloat16* __restrict__ Wcpre,   // frag layout, L2
            const float* __restrict__ bcp,    // (64)
            const float* __restrict__ Wcv,    // (24)
            const float* __restrict__ bcv,    // (1)
            float* __restrict__ Out)          // (1024, 1056) f32
{
  extern __shared__ __align__(16) char smem[];
  const int tid = threadIdx.x;
  const int wave = tid >> 6, lane = tid & 63;
  const int q = lane & 15, g = lane >> 4;
  const int c = wave;
  const int b0 = blockIdx.x * 4;

  f32x4 xa[16];
  #define LOADX(bb) do {                                                        \
    _Pragma("unroll")                                                           \
    for (int _mt = 0; _mt < 2; ++_mt) {                                         \
      const float* _s = X + ((size_t)((bb) * 8 + c)) * 4096                     \
                          + (_mt * 16 + q) * 128 + g * 8;                       \
      _Pragma("unroll")                                                         \
      for (int _ks = 0; _ks < 4; ++_ks) {                                       \
        xa[(_mt * 4 + _ks) * 2 + 0] = *reinterpret_cast<const f32x4*>(_s + _ks * 32);     \
        xa[(_mt * 4 + _ks) * 2 + 1] = *reinterpret_cast<const f32x4*>(_s + _ks * 32 + 4); \
      } } } while (0)

  // issue iter-0 X loads FIRST; they fly under W1 staging + barrier
  LOADX(b0);

  // ---- stage W1 frags from RAW f32 W1; small tensors; sig pads ----
  #pragma unroll
  for (int i = 0; i < 8; ++i) {
    const int p8 = tid + i * 512;
    const int fq = p8 & 15, fg = (p8 >> 4) & 3, fks = (p8 >> 6) & 3;
    const int fnt = (p8 >> 8) & 3, fnc = (p8 >> 10) & 3;
    const float* src = W1 + (fnc * 64 + fnt * 16 + fq) * 128 + fks * 32 + fg * 8;
    *reinterpret_cast<bf16x8*>(smem + L_W1 + p8 * 16) =
        cvt8(*reinterpret_cast<const f32x4*>(src),
             *reinterpret_cast<const f32x4*>(src + 4));
  }
  {
    if (tid < 256)               ((float*)(smem + L_B1))[tid]       = b1[tid];
    if (tid >= 256 && tid < 320) ((float*)(smem + L_BC))[tid - 256] = bcp[tid - 256];
    if (tid >= 320 && tid < 344) ((float*)(smem + L_WV))[tid - 320] = Wcv[tid - 320];
    if (tid == 344)              ((float*)(smem + L_WV))[24]        = bcv[0];
    if (tid >= 384 && tid < 448) {   // zero pad cols [cc][1056..1063] x2 bufs
      const int t = tid - 384, buf = t >> 5, cc = (t & 31) >> 2, k = t & 3;
      *reinterpret_cast<u32*>(
          reinterpret_cast<__hip_bfloat16*>(smem + (buf ? L_SGB : L_SGA))
          + cc * 1064 + 1056 + 2 * k) = 0u;
    }
  }
  BAR_LDS();   // one-time: LDS writes visible; xa loads stay in flight

  __hip_bfloat16* Hb = reinterpret_cast<__hip_bfloat16*>(smem + L_HS) + wave * 2304;
  const float* smB1 = (const float*)(smem + L_B1);
  const float* smBC = (const float*)(smem + L_BC);
  const float* smWV = (const float*)(smem + L_WV);

  #pragma unroll 1
  for (int it = 0; it < 4; ++it) {
    // consume prefetched X -> bf16 frags
    bf16x8 af[2][4];
    #pragma unroll
    for (int f = 0; f < 8; ++f) af[f >> 2][f & 3] = cvt8(xa[2 * f], xa[2 * f + 1]);

    f32x4 acc2[2][4] = {};   // S^T frag: col t = mt*16+q, row s = nt2*16+4g+i

    #pragma unroll 1         // block cross-chunk load hoisting (reg pressure)
    for (int nc = 0; nc < 4; ++nc) {
      // prefetch ALL GEMM2 B-frags for this chunk; GEMM1 covers their L2 latency
      bf16x8 bw2f[2][4];
      #pragma unroll
      for (int ks2 = 0; ks2 < 2; ++ks2)
        #pragma unroll
        for (int nt2 = 0; nt2 < 4; ++nt2)
          bw2f[ks2][nt2] = *reinterpret_cast<const bf16x8*>(
              Wcpre + ((nc * 2 + ks2) * 4 + nt2) * 512 + lane * 8);

      // GEMM1 chunk (swapped): D = W1tile @ X^T -> col=t=q, row=h=4g+i
      f32x4 acc1[2][4] = {};
      #pragma unroll
      for (int ks = 0; ks < 4; ++ks) {
        bf16x8 bw[4];
        #pragma unroll
        for (int nt = 0; nt < 4; ++nt)
          bw[nt] = *reinterpret_cast<const bf16x8*>(
              smem + L_W1 + (((nc * 4 + nt) * 4 + ks) << 10) + lane * 16);
        __builtin_amdgcn_s_setprio(1);
        #pragma unroll
        for (int nt = 0; nt < 4; ++nt) {
          acc1[0][nt] = __builtin_amdgcn_mfma_f32_16x16x32_bf16(bw[nt], af[0][ks], acc1[0][nt], 0, 0, 0);
          acc1[1][nt] = __builtin_amdgcn_mfma_f32_16x16x32_bf16(bw[nt], af[1][ks], acc1[1][nt], 0, 0, 0);
        }
        __builtin_amdgcn_s_setprio(0);
      }
      // +b1, relu -> H chunk [32 t][72 h'], packed b64 writes
      #pragma unroll
      for (int nt = 0; nt < 4; ++nt) {
        const f32x4 b1q = *reinterpret_cast<const f32x4*>(smB1 + nc * 64 + nt * 16 + 4 * g);
        #pragma unroll
        for (int mt = 0; mt < 2; ++mt) {
          u32x2 w;
          w[0] = packbf2(fmaxf(acc1[mt][nt][0] + b1q[0], 0.f),
                         fmaxf(acc1[mt][nt][1] + b1q[1], 0.f));
          w[1] = packbf2(fmaxf(acc1[mt][nt][2] + b1q[2], 0.f),
                         fmaxf(acc1[mt][nt][3] + b1q[3], 0.f));
          *reinterpret_cast<u32x2*>(Hb + (mt * 16 + q) * 72 + nt * 16 + 4 * g) = w;
        }
      }
      // GEMM2 partial (swapped): D = Wc @ H^T -> col=t=q, row=s=4g+i
      #pragma unroll
      for (int ks2 = 0; ks2 < 2; ++ks2) {
        bf16x8 bh[2];
        #pragma unroll
        for (int mt = 0; mt < 2; ++mt)
          bh[mt] = *reinterpret_cast<const bf16x8*>(Hb + (mt * 16 + q) * 72 + ks2 * 32 + g * 8);
        __builtin_amdgcn_s_setprio(1);
        #pragma unroll
        for (int nt2 = 0; nt2 < 4; ++nt2) {
          acc2[0][nt2] = __builtin_amdgcn_mfma_f32_16x16x32_bf16(bw2f[ks2][nt2], bh[0], acc2[0][nt2], 0, 0, 0);
          acc2[1][nt2] = __builtin_amdgcn_mfma_f32_16x16x32_bf16(bw2f[ks2][nt2], bh[1], acc2[1][nt2], 0, 0, 0);
        }
        __builtin_amdgcn_s_setprio(0);
      }
    }

    // issue next batch's X loads AFTER all Wcpre loads of this iteration:
    // vmcnt retires in order, so fragment waits never drain the X prefetch.
    if (it < 3) LOADX(b0 + it + 1);

    // per-wave: S -> own H region [32 t][68 s] (packed b64)
    __hip_bfloat16* Sl = Hb;
    #pragma unroll
    for (int nt2 = 0; nt2 < 4; ++nt2) {
      const f32x4 bcq = *reinterpret_cast<const f32x4*>(smBC + nt2 * 16 + 4 * g);
      #pragma unroll
      for (int mt = 0; mt < 2; ++mt) {
        u32x2 w;
        w[0] = packbf2(acc2[mt][nt2][0] + bcq[0], acc2[mt][nt2][1] + bcq[1]);
        w[1] = packbf2(acc2[mt][nt2][2] + bcq[2], acc2[mt][nt2][3] + bcq[3]);
        *reinterpret_cast<u32x2*>(Sl + (mt * 16 + q) * 68 + nt2 * 16 + 4 * g) = w;
      }
    }

    // overlap-add gather + normalize -> bf16 sig[it&1][c][0..1055], 4/lane
    {
      __hip_bfloat16* sigc = reinterpret_cast<__hip_bfloat16*>(
          smem + ((it & 1) ? L_SGB : L_SGA)) + c * 1064;
      #pragma unroll
      for (int w = 0; w < 5; ++w) {
        const int u = w * 64 + lane;
        if (u < 264) {
          const int p = 4 * u, t = p >> 5, j = p & 31;
          u32x2 r1 = {0u, 0u}, r2 = {0u, 0u};
          if (t < 32) r1 = *reinterpret_cast<const u32x2*>(Sl + t * 68 + j);
          if (t > 0)  r2 = *reinterpret_cast<const u32x2*>(Sl + (t - 1) * 68 + j + 32);
          const float nrm = (t == 0 || t == 32) ? 1.f : 0.5f;
          u32x2 wv;
          wv[0] = packbf2(nrm * (lo16f(r1[0]) + lo16f(r2[0])),
                          nrm * (hi16f(r1[0]) + hi16f(r2[0])));
          wv[1] = packbf2(nrm * (lo16f(r1[1]) + lo16f(r2[1])),
                          nrm * (hi16f(r1[1]) + hi16f(r2[1])));
          *reinterpret_cast<u32x2*>(sigc + p) = wv;
        }
      }
    }

    // paired conv on odd iters: one pass over both batches, 528 quads
    if (it & 1) {
      BAR_LDS();   // both sig buffers complete for all 8 channels
      const float bconv = smWV[24];
      #pragma unroll 1
      for (int rr = 0; rr < 2; ++rr) {
        const int u = tid + rr * 512;
        if (u < 528) {
          const int half = (u >= 264) ? 1 : 0;
          const __hip_bfloat16* sg = reinterpret_cast<const __hip_bfloat16*>(
              smem + (half ? L_SGB : L_SGA));
          const int p0 = (u - half * 264) * 4;
          f32x4 acc = {bconv, bconv, bconv, bconv};
          #pragma unroll
          for (int cc = 0; cc < 8; ++cc) {
            const __hip_bfloat16* row = sg + cc * 1064;
            const u32 wm = (p0 > 0) ? *reinterpret_cast<const u32*>(row + p0 - 2) : 0u;
            const u32x2 wc = *reinterpret_cast<const u32x2*>(row + p0);
            const u32 wr = *reinterpret_cast<const u32*>(row + p0 + 4);
            const float l  = hi16f(wm);
            const float a0 = lo16f(wc[0]), a1 = hi16f(wc[0]);
            const float a2 = lo16f(wc[1]), a3 = hi16f(wc[1]);
            const float r  = lo16f(wr);
            const float w0 = smWV[cc * 3], w1 = smWV[cc * 3 + 1], w2 = smWV[cc * 3 + 2];
            acc[0] = fmaf(w0, l,  fmaf(w1, a0, fmaf(w2, a1, acc[0])));
            acc[1] = fmaf(w0, a0, fmaf(w1, a1, fmaf(w2, a2, acc[1])));
            acc[2] = fmaf(w0, a1, fmaf(w1, a2, fmaf(w2, a3, acc[2])));
            acc[3] = fmaf(w0, a2, fmaf(w1, a3, fmaf(w2, r,  acc[3])));
          }
          *reinterpret_cast<f32x4*>(
              Out + (size_t)(b0 + it - 1 + half) * 1056 + p0) = acc;
        }
      }
      if (it != 3) BAR_LDS();   // conv reads done before next pair's gathers
    }
  }
  #undef LOADX
}

extern "C" void kernel_launch(void* const* d_in, const int* in_sizes, int n_in,
                              void* d_out, int out_size, void* d_ws, size_t ws_size,
                              hipStream_t stream) {
  const float* X    = (const float*)d_in[0];
  const float* W1   = (const float*)d_in[1];
  const float* b1   = (const float*)d_in[2];
  const float* W2   = (const float*)d_in[3];
  const float* b2   = (const float*)d_in[4];
  const float* Winv = (const float*)d_in[5];
  const float* binv = (const float*)d_in[6];
  const float* Wcv  = (const float*)d_in[7];
  const float* bcv  = (const float*)d_in[8];

  __hip_bfloat16* Wcpre = (__hip_bfloat16*)((char*)d_ws + 65536);    // 32768 B
  float*          bcp   = (float*)((char*)d_ws + 98304);             // 256 B

  k_precomp<<<64, 256, 0, stream>>>(W2, b2, Winv, binv, Wcpre, bcp);
  k_gemm<<<256, 512, LDS_SZ, stream>>>(X, W1, b1, Wcpre, bcp, Wcv, bcv,
                                       (float*)d_out);
}